// Round 7
// baseline (95.131 us; speedup 1.0000x reference)
//
#include <hip/hip_runtime.h>
#include <math.h>

// Kaldi LinearResample 16000 -> 22050, LPW=6.
// P=441 phases, STRIDE=320, W=13 taps, tot = 441*3000 = 125 chunks of 24 m.
// R6 structure: block = (batch, 24-m chunk), 512 threads.
//   1) stage contiguous 7700-float input window -> LDS (dense float4, zero-pad
//      OOB; kills all per-output edge guards),
//   2) GPW=3 compute from LDS (5 ds_read_b128 per 3 outputs, weights fixed in
//      registers per thread),
//   3) out-tile in LDS (stride-3 writes, conflict-free) -> dense aligned
//      nontemporal float4 streamout.
// R7 fix: __builtin_nontemporal_store needs a NATIVE vector type, not HIP's
// float4 class -> use ext_vector_type(4) alias for the streamout.
#define ORIG_F 16000
#define NEW_F  22050
#define LPW    6
#define P      441
#define STRIDE 320
#define W      13
#define GPW    3
#define NG     147         // 441/3
#define W20    20
#define MBLK   24          // m per block
#define MCH    125         // 3000/MBLK
#define BATCH  8
#define TILE_F 7700        // 8 + 23*320 + 312 + 20 = 7699 -> 7700 (30.8 KB)
#define OUTT_F (MBLK * P)  // 10584 floats (42.3 KB)

#ifndef M_PI
#define M_PI 3.14159265358979323846
#endif

typedef float f4n __attribute__((ext_vector_type(4)));   // native vec for NT store

__device__ __forceinline__ double kaldi_fi(int p, double* out_t) {
    const double cutoff = 0.99 * 0.5 * (double)ORIG_F;
    const double ww = (double)LPW / (2.0 * cutoff);
    double ot = (double)p / (double)NEW_F;
    *out_t = ot;
    return ceil((ot - ww) * (double)ORIG_F);
}

// One thread per (phase, padded tap j in [0,20)): w20[p][j] = weight applied
// to x[gab[p/3]+j] for phase p (0 outside 13-tap support); gab[g]=fi[3g]&~3.
__global__ void build_table20_kernel(float* __restrict__ w20, int* __restrict__ gab) {
    int idx = blockIdx.x * blockDim.x + threadIdx.x;
    if (idx >= P * W20) return;
    int p = idx / W20;
    int j = idx - p * W20;
    const double cutoff = 0.99 * 0.5 * (double)ORIG_F;
    const double ww = (double)LPW / (2.0 * cutoff);
    double out_t, out_t0;
    double min_i = kaldi_fi(p, &out_t);
    int fi = (int)min_i;
    int p0 = (p / GPW) * GPW;
    int fi0 = (int)kaldi_fi(p0, &out_t0);
    int ab = fi0 & ~3;
    if (j == 0 && p == p0) gab[p / GPW] = ab;
    int jt = ab + j - fi;
    float wf = 0.f;
    if (jt >= 0 && jt < W) {
        double dt = (min_i + (double)jt) / (double)ORIG_F - out_t;
        double wv = 0.0;
        if (fabs(dt) < ww) {
            wv = 0.5 * (1.0 + cos(2.0 * M_PI * cutoff / (double)LPW * dt));
            if (dt != 0.0) wv *= sin(2.0 * M_PI * cutoff * dt) / (M_PI * dt);
            else           wv *= 2.0 * cutoff;
        }
        wv /= (double)ORIG_F;
        wf = (float)wv;
    }
    w20[p * W20 + j] = wf;
}

__device__ __forceinline__ float dot20(const float4& x0, const float4& x1,
                                       const float4& x2, const float4& x3,
                                       const float4& x4, const float4* w) {
    return x0.x*w[0].x + x0.y*w[0].y + x0.z*w[0].z + x0.w*w[0].w
         + x1.x*w[1].x + x1.y*w[1].y + x1.z*w[1].z + x1.w*w[1].w
         + x2.x*w[2].x + x2.y*w[2].y + x2.z*w[2].z + x2.w*w[2].w
         + x3.x*w[3].x + x3.y*w[3].y + x3.z*w[3].z + x3.w*w[3].w
         + x4.x*w[4].x + x4.y*w[4].y + x4.z*w[4].z + x4.w*w[4].w;
}

__global__ __launch_bounds__(512, 4) void resample6_kernel(
    const float* __restrict__ x, const float* __restrict__ w20,
    const int* __restrict__ gab, float* __restrict__ out,
    int n, int tot)
{
    __shared__ float xt[TILE_F];    // input window
    __shared__ float ot[OUTT_F];    // output tile

    const int b  = blockIdx.y;
    const int mc = blockIdx.x;
    const float* __restrict__ xb = x + (size_t)b * n;

    // Tile origin (global float index); S4 % 4 == 0 so float4 loads align.
    const int S4 = mc * (MBLK * STRIDE) - 8;

    // ---- stage input tile (dense, coalesced, zero-padded) ----
    for (int i4 = threadIdx.x; i4 < TILE_F / 4; i4 += 512) {
        const int gi = S4 + i4 * 4;
        float4 v;
        if (gi >= 0 && gi + 3 < n) {
            v = *(const float4*)(xb + gi);
        } else {
            float s[4];
            #pragma unroll
            for (int q = 0; q < 4; ++q) {
                int ii = gi + q;
                s[q] = (ii >= 0 && ii < n) ? xb[ii] : 0.f;
            }
            v = make_float4(s[0], s[1], s[2], s[3]);
        }
        *(float4*)(xt + i4 * 4) = v;
    }

    // ---- per-thread weights (independent of staging; issues in parallel) ----
    const int t = threadIdx.x;
    float4 w[15];
    int Lbase = 0, obase = 0;
    const bool active = (t < P);
    if (active) {
        const int g     = t % NG;     // phase group
        const int third = t / NG;     // which 8-m slice
        const float4* wp = (const float4*)(w20 + g * (GPW * W20));
        #pragma unroll
        for (int i = 0; i < 15; ++i) w[i] = wp[i];
        // LDS float index for (g, m_local): gab[g] + 8 + m_local*320
        Lbase = gab[g] + 8 + third * (8 * STRIDE);
        obase = third * 8 * P + GPW * g;
    }
    __syncthreads();

    // ---- compute: 3 outputs x 8 m-steps per active thread ----
    if (active) {
        #pragma unroll 1
        for (int k = 0; k < 8; ++k) {
            const float4* q4 = (const float4*)(xt + Lbase);
            float4 x0 = q4[0], x1 = q4[1], x2 = q4[2], x3 = q4[3], x4 = q4[4];
            float a0 = dot20(x0, x1, x2, x3, x4, &w[0]);
            float a1 = dot20(x0, x1, x2, x3, x4, &w[5]);
            float a2 = dot20(x0, x1, x2, x3, x4, &w[10]);
            ot[obase]     = a0;       // stride-3 word writes: conflict-free
            ot[obase + 1] = a1;
            ot[obase + 2] = a2;
            Lbase += STRIDE; obase += P;
        }
    }
    __syncthreads();

    // ---- streamout: dense aligned nontemporal float4 ----
    float* __restrict__ dst = out + (size_t)b * tot + (size_t)mc * OUTT_F;
    for (int i4 = threadIdx.x; i4 < OUTT_F / 4; i4 += 512) {
        f4n v = *(const f4n*)(ot + i4 * 4);
        __builtin_nontemporal_store(v, (f4n*)(dst + i4 * 4));
    }
}

extern "C" void kernel_launch(void* const* d_in, const int* in_sizes, int n_in,
                              void* d_out, int out_size, void* d_ws, size_t ws_size,
                              hipStream_t stream) {
    const float* x = (const float*)d_in[0];
    float* out = (float*)d_out;

    const int n = in_sizes[0] / BATCH;     // 960000

    // Kaldi GetNumOutputSamples
    long long interval = (long long)n * P;
    long long last = interval / STRIDE;
    if (last * STRIDE == interval) last -= 1;
    const int tot = (int)(last + 1);       // 1,323,000 = 125 * 10584

    float* w20 = (float*)d_ws;
    int*   gab = (int*)((char*)d_ws + (size_t)P * W20 * sizeof(float));

    build_table20_kernel<<<(P * W20 + 255) / 256, 256, 0, stream>>>(w20, gab);

    dim3 grid(MCH, BATCH);                 // 125 x 8 = 1000 blocks
    resample6_kernel<<<grid, 512, 0, stream>>>(x, w20, gab, out, n, tot);
}

// Round 8
// 36.966 us; speedup vs baseline: 2.5735x; 2.5735x over previous
//
#include <hip/hip_runtime.h>
#include <math.h>

// Kaldi LinearResample 16000 -> 22050, LPW=6.
// P=441 phases, STRIDE=320, W=13 taps, tot = 441*3000 = 125 chunks of 24 m.
// R8 structure: block = (batch, 24-m chunk), 448 threads (7 waves).
//   1) stage contiguous 7700-float input window -> LDS (dense float4,
//      zero-padded OOB; kills all per-output edge guards),
//   2) thread t<441 (g=t%147 phase-group, third=t/147 m-slice) computes
//      GPW=3 outputs x 8 m-steps from LDS (5 ds_read_b128 per 3 outputs,
//      15 float4 weights in registers),
//   3) DIRECT stores ob[t..t+2] (merge to dwordx3; wave = 192 contiguous
//      floats; L2 write-back coalesces to full lines).
// R7 lesson: nontemporal float4 stores caused 4x RMW amplification at HBM
// (WRITE 157MB vs 42MB, FETCH +164MB) -> never NT-store partial lines.
#define ORIG_F 16000
#define NEW_F  22050
#define LPW    6
#define P      441
#define STRIDE 320
#define W      13
#define GPW    3
#define NG     147         // 441/3
#define W20    20
#define MBLK   24          // m per block
#define MCH    125         // 3000/MBLK
#define BATCH  8
#define TILE_F 7700        // covers gab[0]+8 .. gab[146]+8+23*320+20 (30.8 KB)

#ifndef M_PI
#define M_PI 3.14159265358979323846
#endif

__device__ __forceinline__ double kaldi_fi(int p, double* out_t) {
    const double cutoff = 0.99 * 0.5 * (double)ORIG_F;
    const double ww = (double)LPW / (2.0 * cutoff);
    double ot = (double)p / (double)NEW_F;
    *out_t = ot;
    return ceil((ot - ww) * (double)ORIG_F);
}

// One thread per (phase, padded tap j in [0,20)): w20[p][j] = weight applied
// to x[gab[p/3]+j] for phase p (0 outside 13-tap support); gab[g]=fi[3g]&~3.
__global__ void build_table20_kernel(float* __restrict__ w20, int* __restrict__ gab) {
    int idx = blockIdx.x * blockDim.x + threadIdx.x;
    if (idx >= P * W20) return;
    int p = idx / W20;
    int j = idx - p * W20;
    const double cutoff = 0.99 * 0.5 * (double)ORIG_F;
    const double ww = (double)LPW / (2.0 * cutoff);
    double out_t, out_t0;
    double min_i = kaldi_fi(p, &out_t);
    int fi = (int)min_i;
    int p0 = (p / GPW) * GPW;
    int fi0 = (int)kaldi_fi(p0, &out_t0);
    int ab = fi0 & ~3;
    if (j == 0 && p == p0) gab[p / GPW] = ab;
    int jt = ab + j - fi;
    float wf = 0.f;
    if (jt >= 0 && jt < W) {
        double dt = (min_i + (double)jt) / (double)ORIG_F - out_t;
        double wv = 0.0;
        if (fabs(dt) < ww) {
            wv = 0.5 * (1.0 + cos(2.0 * M_PI * cutoff / (double)LPW * dt));
            if (dt != 0.0) wv *= sin(2.0 * M_PI * cutoff * dt) / (M_PI * dt);
            else           wv *= 2.0 * cutoff;
        }
        wv /= (double)ORIG_F;
        wf = (float)wv;
    }
    w20[p * W20 + j] = wf;
}

__device__ __forceinline__ float dot20(const float4& x0, const float4& x1,
                                       const float4& x2, const float4& x3,
                                       const float4& x4, const float4* w) {
    return x0.x*w[0].x + x0.y*w[0].y + x0.z*w[0].z + x0.w*w[0].w
         + x1.x*w[1].x + x1.y*w[1].y + x1.z*w[1].z + x1.w*w[1].w
         + x2.x*w[2].x + x2.y*w[2].y + x2.z*w[2].z + x2.w*w[2].w
         + x3.x*w[3].x + x3.y*w[3].y + x3.z*w[3].z + x3.w*w[3].w
         + x4.x*w[4].x + x4.y*w[4].y + x4.z*w[4].z + x4.w*w[4].w;
}

__global__ __launch_bounds__(448) void resample8_kernel(
    const float* __restrict__ x, const float* __restrict__ w20,
    const int* __restrict__ gab, float* __restrict__ out,
    int n, int tot)
{
    __shared__ float xt[TILE_F];

    const int b  = blockIdx.y;
    const int mc = blockIdx.x;
    const float* __restrict__ xb = x + (size_t)b * n;

    // Tile origin (global float index); S4 % 4 == 0 so float4 loads align.
    const int S4 = mc * (MBLK * STRIDE) - 8;

    // ---- stage input tile (dense, coalesced, zero-padded) ----
    for (int i4 = threadIdx.x; i4 < TILE_F / 4; i4 += 448) {
        const int gi = S4 + i4 * 4;
        float4 v;
        if (gi >= 0 && gi + 3 < n) {
            v = *(const float4*)(xb + gi);
        } else {
            float s[4];
            #pragma unroll
            for (int q = 0; q < 4; ++q) {
                int ii = gi + q;
                s[q] = (ii >= 0 && ii < n) ? xb[ii] : 0.f;
            }
            v = make_float4(s[0], s[1], s[2], s[3]);
        }
        *(float4*)(xt + i4 * 4) = v;
    }

    // ---- per-thread weights (independent of staging; overlaps the loads) ----
    const int t = threadIdx.x;
    float4 w[15];
    int Lbase = 0;
    int tout = 0;
    const bool active = (t < P);
    if (active) {
        const int g     = t % NG;     // phase group
        const int third = t / NG;     // which 8-m slice
        const float4* wp = (const float4*)(w20 + g * (GPW * W20));
        #pragma unroll
        for (int i = 0; i < 15; ++i) w[i] = wp[i];
        Lbase = gab[g] + 8 + third * (8 * STRIDE);
        tout  = (mc * MBLK + third * 8) * P + GPW * g;
    }
    __syncthreads();

    // ---- compute: 3 outputs x 8 m-steps, direct dwordx3 stores ----
    if (active) {
        float* __restrict__ ob = out + (size_t)b * tot;
        #pragma unroll 1
        for (int k = 0; k < 8; ++k) {
            const float4* q4 = (const float4*)(xt + Lbase);
            float4 x0 = q4[0], x1 = q4[1], x2 = q4[2], x3 = q4[3], x4 = q4[4];
            float a0 = dot20(x0, x1, x2, x3, x4, &w[0]);
            float a1 = dot20(x0, x1, x2, x3, x4, &w[5]);
            float a2 = dot20(x0, x1, x2, x3, x4, &w[10]);
            ob[tout]     = a0;        // merges to global_store_dwordx3
            ob[tout + 1] = a1;
            ob[tout + 2] = a2;
            Lbase += STRIDE; tout += P;
        }
    }
}

extern "C" void kernel_launch(void* const* d_in, const int* in_sizes, int n_in,
                              void* d_out, int out_size, void* d_ws, size_t ws_size,
                              hipStream_t stream) {
    const float* x = (const float*)d_in[0];
    float* out = (float*)d_out;

    const int n = in_sizes[0] / BATCH;     // 960000

    // Kaldi GetNumOutputSamples
    long long interval = (long long)n * P;
    long long last = interval / STRIDE;
    if (last * STRIDE == interval) last -= 1;
    const int tot = (int)(last + 1);       // 1,323,000 = 125 * 10584

    float* w20 = (float*)d_ws;
    int*   gab = (int*)((char*)d_ws + (size_t)P * W20 * sizeof(float));

    build_table20_kernel<<<(P * W20 + 255) / 256, 256, 0, stream>>>(w20, gab);

    dim3 grid(MCH, BATCH);                 // 125 x 8 = 1000 blocks
    resample8_kernel<<<grid, 448, 0, stream>>>(x, w20, gab, out, n, tot);
}